// Round 1
// 180.079 us; speedup vs baseline: 1.0038x; 1.0038x over previous
//
#include <hip/hip_runtime.h>
#include <math.h>

typedef __attribute__((ext_vector_type(8))) short short8;   // 8 x bf16 (4 VGPRs)
typedef __attribute__((ext_vector_type(4))) float f32x4;    // MFMA acc

constexpr int B  = 8;
constexpr int N  = 1024;
constexpr int D  = 512;
constexpr int H  = 8;
constexpr int DH = 64;
constexpr int M_ROWS = 8192;
constexpr float EPS_DIST = 1e-8f;
constexpr float EPS_LN   = 1e-5f;

// fp32 -> bf16 bits (RNE)
__device__ inline unsigned short bfbits(float f) {
    union { float f; unsigned u; } v; v.f = f;
    unsigned r = v.u + 0x7fffu + ((v.u >> 16) & 1u);
    return (unsigned short)(r >> 16);
}
__device__ inline float bf2f(unsigned short s) {
    union { unsigned u; float f; } v; v.u = ((unsigned)s) << 16; return v.f;
}

// async 16B global->LDS (per lane; LDS dest = wave-uniform base + lane*16)
__device__ inline void async_ld16(unsigned short* lds, const unsigned short* g) {
    __builtin_amdgcn_global_load_lds(
        (const __attribute__((address_space(1))) unsigned int*)(g),
        (__attribute__((address_space(3))) unsigned int*)(lds),
        16, 0, 0);
}

// ---------------------------------------------------------------------------
// Fused: blocks 0..255 transpose+convert the 4 weights to bf16;
// blocks 256.. do LN1 (x -> h bf16), wave-per-row (4 rows / 256-thr block),
// float4 loads + shuffle reduce, no LDS, no barriers.
// ---------------------------------------------------------------------------
__global__ __launch_bounds__(256) void prep_kernel(const float* __restrict__ Wq,
                                                   const float* __restrict__ Wk,
                                                   const float* __restrict__ Wv,
                                                   const float* __restrict__ Wo,
                                                   unsigned short* __restrict__ WtAll,
                                                   const float* __restrict__ x,
                                                   const float* __restrict__ ln1_g,
                                                   const float* __restrict__ ln1_b,
                                                   unsigned short* __restrict__ h_bf) {
    const int bxg = blockIdx.x;
    if (bxg < 256) {
        int sub = bxg >> 6;
        const float* W = sub == 0 ? Wq : sub == 1 ? Wk : sub == 2 ? Wv : Wo;
        unsigned short* Wt = WtAll + (size_t)sub * 262144;
        int t = (bxg & 63) * 256 + threadIdx.x;
        int tn = t & 127, tk = t >> 7;
        int k = tk * 4, n = tn * 4;
        float4 r0 = *(const float4*)&W[(size_t)(k + 0) * 512 + n];
        float4 r1 = *(const float4*)&W[(size_t)(k + 1) * 512 + n];
        float4 r2 = *(const float4*)&W[(size_t)(k + 2) * 512 + n];
        float4 r3 = *(const float4*)&W[(size_t)(k + 3) * 512 + n];
        ushort4 c;
        c.x = bfbits(r0.x); c.y = bfbits(r1.x); c.z = bfbits(r2.x); c.w = bfbits(r3.x);
        *(ushort4*)&Wt[(size_t)(n + 0) * 512 + k] = c;
        c.x = bfbits(r0.y); c.y = bfbits(r1.y); c.z = bfbits(r2.y); c.w = bfbits(r3.y);
        *(ushort4*)&Wt[(size_t)(n + 1) * 512 + k] = c;
        c.x = bfbits(r0.z); c.y = bfbits(r1.z); c.z = bfbits(r2.z); c.w = bfbits(r3.z);
        *(ushort4*)&Wt[(size_t)(n + 2) * 512 + k] = c;
        c.x = bfbits(r0.w); c.y = bfbits(r1.w); c.z = bfbits(r2.w); c.w = bfbits(r3.w);
        *(ushort4*)&Wt[(size_t)(n + 3) * 512 + k] = c;
    } else {
        const int w = threadIdx.x >> 6, lane = threadIdx.x & 63;
        const int row = (bxg - 256) * 4 + w;
        const float4* xr = (const float4*)(x + (size_t)row * D);
        float4 a = xr[lane], b2 = xr[lane + 64];
        float s = a.x + a.y + a.z + a.w + b2.x + b2.y + b2.z + b2.w;
        #pragma unroll
        for (int o = 1; o < 64; o <<= 1) s += __shfl_xor(s, o, 64);
        const float mu = s * (1.0f / 512.0f);
        float d0 = a.x - mu, d1 = a.y - mu, d2 = a.z - mu, d3 = a.w - mu;
        float e0 = b2.x - mu, e1 = b2.y - mu, e2 = b2.z - mu, e3 = b2.w - mu;
        float vs = d0*d0 + d1*d1 + d2*d2 + d3*d3 + e0*e0 + e1*e1 + e2*e2 + e3*e3;
        #pragma unroll
        for (int o = 1; o < 64; o <<= 1) vs += __shfl_xor(vs, o, 64);
        const float rstd = rsqrtf(vs * (1.0f / 512.0f) + EPS_LN);
        const float4* g4 = (const float4*)ln1_g;
        const float4* b4 = (const float4*)ln1_b;
        float4 ga = g4[lane], gb = g4[lane + 64];
        float4 ba = b4[lane], bb = b4[lane + 64];
        ushort4 u;
        u.x = bfbits(d0 * rstd * ga.x + ba.x);
        u.y = bfbits(d1 * rstd * ga.y + ba.y);
        u.z = bfbits(d2 * rstd * ga.z + ba.z);
        u.w = bfbits(d3 * rstd * ga.w + ba.w);
        *(ushort4*)&h_bf[(size_t)row * 512 + lane * 4] = u;
        u.x = bfbits(e0 * rstd * gb.x + bb.x);
        u.y = bfbits(e1 * rstd * gb.y + bb.y);
        u.z = bfbits(e2 * rstd * gb.z + bb.z);
        u.w = bfbits(e3 * rstd * gb.w + bb.w);
        *(ushort4*)&h_bf[(size_t)row * 512 + 256 + lane * 4] = u;
    }
}

// ---------------------------------------------------------------------------
// LN2: y = LN(bf16 Y0 + fp32 x) -> fp32 out. Wave-per-row, vectorized,
// no barriers.
// ---------------------------------------------------------------------------
__global__ __launch_bounds__(256) void ln2_kernel(const unsigned short* __restrict__ y0,
                                                  const float* __restrict__ res,
                                                  const float* __restrict__ gamma,
                                                  const float* __restrict__ beta,
                                                  float* __restrict__ out) {
    const int w = threadIdx.x >> 6, lane = threadIdx.x & 63;
    const int row = blockIdx.x * 4 + w;
    const ushort4* y4 = (const ushort4*)(y0 + (size_t)row * D);
    const float4*  r4 = (const float4*)(res + (size_t)row * D);
    ushort4 ya = y4[lane], yb = y4[lane + 64];
    float4  ra = r4[lane], rb = r4[lane + 64];
    float v0 = bf2f(ya.x) + ra.x, v1 = bf2f(ya.y) + ra.y;
    float v2 = bf2f(ya.z) + ra.z, v3 = bf2f(ya.w) + ra.w;
    float v4 = bf2f(yb.x) + rb.x, v5 = bf2f(yb.y) + rb.y;
    float v6 = bf2f(yb.z) + rb.z, v7 = bf2f(yb.w) + rb.w;
    float s = v0 + v1 + v2 + v3 + v4 + v5 + v6 + v7;
    #pragma unroll
    for (int o = 1; o < 64; o <<= 1) s += __shfl_xor(s, o, 64);
    const float mu = s * (1.0f / 512.0f);
    v0 -= mu; v1 -= mu; v2 -= mu; v3 -= mu;
    v4 -= mu; v5 -= mu; v6 -= mu; v7 -= mu;
    float vs = v0*v0 + v1*v1 + v2*v2 + v3*v3 + v4*v4 + v5*v5 + v6*v6 + v7*v7;
    #pragma unroll
    for (int o = 1; o < 64; o <<= 1) vs += __shfl_xor(vs, o, 64);
    const float rstd = rsqrtf(vs * (1.0f / 512.0f) + EPS_LN);
    const float4* g4 = (const float4*)gamma;
    const float4* b4 = (const float4*)beta;
    float4 ga = g4[lane], gb = g4[lane + 64];
    float4 ba = b4[lane], bb = b4[lane + 64];
    float4 o1, o2;
    o1.x = v0 * rstd * ga.x + ba.x; o1.y = v1 * rstd * ga.y + ba.y;
    o1.z = v2 * rstd * ga.z + ba.z; o1.w = v3 * rstd * ga.w + ba.w;
    o2.x = v4 * rstd * gb.x + bb.x; o2.y = v5 * rstd * gb.y + bb.y;
    o2.z = v6 * rstd * gb.z + bb.z; o2.w = v7 * rstd * gb.w + bb.w;
    float4* orow = (float4*)(out + (size_t)row * D);
    orow[lane]      = o1;
    orow[lane + 64] = o2;
}

// ---------------------------------------------------------------------------
// MTx128-tile bf16 MFMA GEMM, BK=64. A[M,512] @ Wt[n][k]. 1D grid, by=id&(RB-1)
// (XCD-local A reuse). MODE 0 (MT=64): bf16 out row-major.
// MODE 1 (MT=128): fused QKV epilogue (N=1536): Q,K -> [bh][n][dh] + sumsq,
// V -> [bh][dh][n] via LDS transpose.
// ---------------------------------------------------------------------------
template <int MODE, int MT>
__global__ __launch_bounds__(256) void gemm128(const unsigned short* __restrict__ A,
                                               const unsigned short* __restrict__ Wt,
                                               const float* __restrict__ bias0,
                                               const float* __restrict__ bias1,
                                               const float* __restrict__ bias2,
                                               void* __restrict__ o0,
                                               unsigned short* __restrict__ Ko,
                                               unsigned short* __restrict__ Vo,
                                               float* __restrict__ sq0,
                                               float* __restrict__ sq1) {
    constexpr int RB = M_ROWS / MT;
    constexpr int NI = MT / 32;
    constexpr int ASZ = MT * 64, BSZ = 128 * 64;
    constexpr int SMSZ = (MODE == 1) ? ((ASZ + BSZ > 18432) ? ASZ + BSZ : 18432)
                                     : (ASZ + BSZ);
    __shared__ unsigned short smem[SMSZ];
    unsigned short* As = smem;
    unsigned short* Bs = smem + ASZ;

    const int id = blockIdx.x;
    const int by = id & (RB - 1), bx = id / RB;
    const int tid = threadIdx.x;
    const int lane = tid & 63, wv = tid >> 6;
    const int quad = lane >> 4, l15 = lane & 15;
    const int row0 = by * MT, col0 = bx * 128;
    const int wm = (wv & 1) * (MT / 2), wn = (wv >> 1) * 64;

    f32x4 acc[NI][4];
    #pragma unroll
    for (int i = 0; i < NI; ++i)
        #pragma unroll
        for (int j = 0; j < 4; ++j) acc[i][j] = (f32x4){0.f, 0.f, 0.f, 0.f};

    const unsigned short* Ag = A  + (size_t)row0 * 512;
    const unsigned short* Bg = Wt + (size_t)col0 * 512;

    for (int k0 = 0; k0 < 512; k0 += 64) {
        __syncthreads();
        #pragma unroll
        for (int c = 0; c < ASZ / 2048; ++c) {
            int fu = c * 2048 + tid * 8;
            int r = fu >> 6, ko = fu & 63;
            async_ld16(As + fu, Ag + (size_t)r * 512 + k0 + ko);
        }
        #pragma unroll
        for (int c = 0; c < BSZ / 2048; ++c) {
            int fu = c * 2048 + tid * 8;
            int r = fu >> 6, ko = fu & 63;
            async_ld16(Bs + fu, Bg + (size_t)r * 512 + k0 + ko);
        }
        __syncthreads();

        #pragma unroll
        for (int ks = 0; ks < 2; ++ks) {
            short8 af[NI], bf[4];
            #pragma unroll
            for (int i = 0; i < NI; ++i)
                af[i] = *(const short8*)&As[(wm + i * 16 + l15) * 64 + ks * 32 + quad * 8];
            #pragma unroll
            for (int j = 0; j < 4; ++j)
                bf[j] = *(const short8*)&Bs[(wn + j * 16 + l15) * 64 + ks * 32 + quad * 8];
            #pragma unroll
            for (int i = 0; i < NI; ++i)
                #pragma unroll
                for (int j = 0; j < 4; ++j)
                    acc[i][j] = __builtin_amdgcn_mfma_f32_16x16x32_bf16(af[i], bf[j], acc[i][j], 0, 0, 0);
        }
    }

    if (MODE == 0) {
        unsigned short* C = (unsigned short*)o0;
        #pragma unroll
        for (int i = 0; i < NI; ++i)
            #pragma unroll
            for (int j = 0; j < 4; ++j) {
                int col = col0 + wn + j * 16 + l15;
                float bv = bias0[col];
                #pragma unroll
                for (int r = 0; r < 4; ++r) {
                    int row = row0 + wm + i * 16 + quad * 4 + r;
                    C[(size_t)row * 512 + col] = bfbits(acc[i][j][r] + bv);
                }
            }
    } else {
        const int colg = col0 + wn;
        const int seg = colg >> 9;                 // 0=Q 1=K 2=V
        const int hh = (colg & 511) >> 6;
        const float* bias = seg == 0 ? bias0 : seg == 1 ? bias1 : bias2;

        if (seg < 2) {
            unsigned short* dst = seg == 0 ? (unsigned short*)o0 : Ko;
            float* sq = seg == 0 ? sq0 : sq1;
            #pragma unroll
            for (int i = 0; i < NI; ++i) {
                const int m0 = row0 + wm + i * 16 + quad * 4;
                float ss[4] = {0.f, 0.f, 0.f, 0.f};
                #pragma unroll
                for (int j = 0; j < 4; ++j) {
                    float bvj = bias[hh * 64 + j * 16 + l15];
                    #pragma unroll
                    for (int r = 0; r < 4; ++r) {
                        float v = acc[i][j][r] + bvj;
                        unsigned short ub = bfbits(v);
                        float vr = bf2f(ub);
                        ss[r] += vr * vr;
                        int m = m0 + r;
                        int b_ = m >> 10, n_ = m & 1023;
                        dst[((size_t)((b_ * 8 + hh) * 1024) + n_) * 64 + j * 16 + l15] = ub;
                    }
                }
                #pragma unroll
                for (int r = 0; r < 4; ++r) {
                    float s = ss[r];
                    s += __shfl_xor(s, 1, 64);
                    s += __shfl_xor(s, 2, 64);
                    s += __shfl_xor(s, 4, 64);
                    s += __shfl_xor(s, 8, 64);
                    if (l15 == 0) {
                        int m = m0 + r;
                        sq[(size_t)((m >> 10) * 8 + hh) * 1024 + (m & 1023)] = s;
                    }
                }
            }
        } else {
            // V: transpose through per-wave LDS region, then coalesced stores
            __syncthreads();   // whole block is V (uniform): safe
            unsigned short* T = smem + wv * 4608;  // [64 d][72]
            #pragma unroll
            for (int i = 0; i < NI; ++i)
                #pragma unroll
                for (int j = 0; j < 4; ++j) {
                    float bvj = bias[hh * 64 + j * 16 + l15];
                    ushort4 pk;
                    pk.x = bfbits(acc[i][j][0] + bvj);
                    pk.y = bfbits(acc[i][j][1] + bvj);
                    pk.z = bfbits(acc[i][j][2] + bvj);
                    pk.w = bfbits(acc[i][j][3] + bvj);
                    *(ushort4*)&T[(j * 16 + l15) * 72 + i * 16 + quad * 4] = pk;
                }
            const int b_ = (row0 + wm) >> 10;
            const int nbase = (row0 + wm) & 1023;
            unsigned short* Vg = Vo + ((size_t)((b_ * 8 + hh) * 64)) * 1024 + nbase;
            #pragma unroll
            for (int it = 0; it < 8; ++it) {
                int dl = it * 8 + (lane >> 3);
                int nl = (lane & 7) * 8;
                uint4 v = *(const uint4*)&T[dl * 72 + nl];
                *(uint4*)&Vg[(size_t)dl * 1024 + nl] = v;
            }
        }
    }
}

// ---------------------------------------------------------------------------
// MFMA distance attention. Block = 4 waves (256 thr), 128 q rows, 32 q/wave
// (two 16-row fragment groups) -> K/V LDS fragment reads amortized over 2x
// the MFMA work vs 16 q/wave. V pre-transposed [bh][dh][n]. Double-buffered
// K/V + register prefetch; one barrier per key-tile. bh = id&63.
// P stored via truncation (1 op); denominator from raw p.
// ---------------------------------------------------------------------------
__global__ __launch_bounds__(256) void attn_kernel(const unsigned short* __restrict__ Q,
                                                   const unsigned short* __restrict__ K,
                                                   const unsigned short* __restrict__ Vt,
                                                   const float* __restrict__ qsq,
                                                   const float* __restrict__ ksq,
                                                   unsigned short* __restrict__ O) {
    __shared__ unsigned short Ks[2][64][72];
    __shared__ unsigned short Vs[2][64][72];
    __shared__ unsigned short Ps[4][32][72];
    __shared__ float ksq_s[2][64];

    const int id = blockIdx.x;
    const int bh = id & 63, qb = id >> 6;
    const int q0 = qb * 128;
    const int tid = threadIdx.x;
    const int lane = tid & 63, w = tid >> 6;
    const int quad = lane >> 4, l15 = lane & 15;
    const int b_ = bh >> 3, h_ = bh & 7;

    const unsigned short* Qb = Q  + (size_t)bh * N * DH;
    const unsigned short* Kb = K  + (size_t)bh * N * DH;
    const unsigned short* Vb = Vt + (size_t)bh * DH * N;

    // Q fragments: wave covers rows q0 + w*32 + qh*16 + l15
    short8 qf[2][2];
    #pragma unroll
    for (int qh = 0; qh < 2; ++qh) {
        const unsigned short* qp = Qb + (size_t)(q0 + w * 32 + qh * 16 + l15) * 64 + quad * 8;
        qf[qh][0] = *(const short8*)qp;
        qf[qh][1] = *(const short8*)(qp + 32);
    }
    float qe[2][4];
    #pragma unroll
    for (int qh = 0; qh < 2; ++qh)
        #pragma unroll
        for (int r = 0; r < 4; ++r)
            qe[qh][r] = qsq[bh * N + q0 + w * 32 + qh * 16 + quad * 4 + r] + EPS_DIST;

    f32x4 oacc[2][4];
    #pragma unroll
    for (int qh = 0; qh < 2; ++qh)
        #pragma unroll
        for (int dt = 0; dt < 4; ++dt) oacc[qh][dt] = (f32x4){0.f, 0.f, 0.f, 0.f};
    float dpart[2][4] = {};

    // staging: 256 threads, 2 x 16B each for K and V
    const int e0 = tid, e1 = tid + 256;
    const int r0s = e0 >> 3, c0s = (e0 & 7) * 8;
    const int r1s = e1 >> 3, c1s = (e1 & 7) * 8;
    uint4 kreg0, kreg1, vreg0, vreg1;
    float ksreg = 0.f;

    kreg0 = *(const uint4*)(Kb + (size_t)r0s * 64 + c0s);
    kreg1 = *(const uint4*)(Kb + (size_t)r1s * 64 + c1s);
    vreg0 = *(const uint4*)(Vb + (size_t)r0s * N + c0s);
    vreg1 = *(const uint4*)(Vb + (size_t)r1s * N + c1s);
    if (tid < 64) ksreg = ksq[bh * N + tid];

    *(uint4*)&Ks[0][r0s][c0s] = kreg0;
    *(uint4*)&Ks[0][r1s][c1s] = kreg1;
    *(uint4*)&Vs[0][r0s][c0s] = vreg0;
    *(uint4*)&Vs[0][r1s][c1s] = vreg1;
    if (tid < 64) ksq_s[0][tid] = ksreg;
    __syncthreads();

    for (int kt = 0; kt < 16; ++kt) {
        const int cur = kt & 1;
        if (kt < 15) {
            kreg0 = *(const uint4*)(Kb + (size_t)((kt + 1) * 64 + r0s) * 64 + c0s);
            kreg1 = *(const uint4*)(Kb + (size_t)((kt + 1) * 64 + r1s) * 64 + c1s);
            vreg0 = *(const uint4*)(Vb + (size_t)r0s * N + (kt + 1) * 64 + c0s);
            vreg1 = *(const uint4*)(Vb + (size_t)r1s * N + (kt + 1) * 64 + c1s);
            if (tid < 64) ksreg = ksq[bh * N + (kt + 1) * 64 + tid];
        }

        // scores + transform -> Ps  (32 q x 64 keys per wave)
        #pragma unroll
        for (int kb = 0; kb < 4; ++kb) {
            short8 kf0 = *(const short8*)&Ks[cur][kb * 16 + l15][quad * 8];
            short8 kf1 = *(const short8*)&Ks[cur][kb * 16 + l15][32 + quad * 8];
            float ks2 = ksq_s[cur][kb * 16 + l15];
            #pragma unroll
            for (int qh = 0; qh < 2; ++qh) {
                f32x4 sa = (f32x4){0.f, 0.f, 0.f, 0.f};
                sa = __builtin_amdgcn_mfma_f32_16x16x32_bf16(qf[qh][0], kf0, sa, 0, 0, 0);
                sa = __builtin_amdgcn_mfma_f32_16x16x32_bf16(qf[qh][1], kf1, sa, 0, 0, 0);
                #pragma unroll
                for (int r = 0; r < 4; ++r) {
                    float d2 = fmaf(-2.0f, sa[r], qe[qh][r] + ks2);
                    d2 = fmaxf(d2, EPS_DIST);
                    float p = __expf(-__builtin_amdgcn_sqrtf(d2));
                    dpart[qh][r] += p;
                    union { float f; unsigned u; } pu; pu.f = p;
                    Ps[w][qh * 16 + quad * 4 + r][kb * 16 + l15] = (unsigned short)(pu.u >> 16);
                }
            }
        }

        // PV: 16 MFMA per wave per kt on 16 b128 V/P reads
        short8 vf[4][2];
        #pragma unroll
        for (int dt = 0; dt < 4; ++dt)
            #pragma unroll
            for (int kc = 0; kc < 2; ++kc)
                vf[dt][kc] = *(const short8*)&Vs[cur][dt * 16 + l15][kc * 32 + quad * 8];
        #pragma unroll
        for (int kc = 0; kc < 2; ++kc) {
            short8 pf0 = *(const short8*)&Ps[w][l15][kc * 32 + quad * 8];
            short8 pf1 = *(const short8*)&Ps[w][16 + l15][kc * 32 + quad * 8];
            #pragma unroll
            for (int dt = 0; dt < 4; ++dt) {
                oacc[0][dt] = __builtin_amdgcn_mfma_f32_16x16x32_bf16(pf0, vf[dt][kc], oacc[0][dt], 0, 0, 0);
                oacc[1][dt] = __builtin_amdgcn_mfma_f32_16x16x32_bf16(pf1, vf[dt][kc], oacc[1][dt], 0, 0, 0);
            }
        }

        if (kt < 15) {
            *(uint4*)&Ks[cur ^ 1][r0s][c0s] = kreg0;
            *(uint4*)&Ks[cur ^ 1][r1s][c1s] = kreg1;
            *(uint4*)&Vs[cur ^ 1][r0s][c0s] = vreg0;
            *(uint4*)&Vs[cur ^ 1][r1s][c1s] = vreg1;
            if (tid < 64) ksq_s[cur ^ 1][tid] = ksreg;
        }
        __syncthreads();
    }

    float rinv[2][4];
    #pragma unroll
    for (int qh = 0; qh < 2; ++qh)
        #pragma unroll
        for (int r = 0; r < 4; ++r) {
            float s = dpart[qh][r];
            s += __shfl_xor(s, 1, 64);
            s += __shfl_xor(s, 2, 64);
            s += __shfl_xor(s, 4, 64);
            s += __shfl_xor(s, 8, 64);
            rinv[qh][r] = __builtin_amdgcn_rcpf(s);
        }

    #pragma unroll
    for (int qh = 0; qh < 2; ++qh)
        #pragma unroll
        for (int dt = 0; dt < 4; ++dt)
            #pragma unroll
            for (int r = 0; r < 4; ++r) {
                int n_ = q0 + w * 32 + qh * 16 + quad * 4 + r;
                O[((size_t)(b_ * N + n_) * D) + h_ * DH + dt * 16 + l15] =
                    bfbits(oacc[qh][dt][r] * rinv[qh][r]);
            }
}

// ---------------------------------------------------------------------------
extern "C" void kernel_launch(void* const* d_in, const int* in_sizes, int n_in,
                              void* d_out, int out_size, void* d_ws, size_t ws_size,
                              hipStream_t stream) {
    const float* x     = (const float*)d_in[0];
    const float* Wq    = (const float*)d_in[1];
    const float* Wk    = (const float*)d_in[2];
    const float* Wv    = (const float*)d_in[3];
    const float* Wo    = (const float*)d_in[4];
    const float* bq    = (const float*)d_in[5];
    const float* bk    = (const float*)d_in[6];
    const float* bv    = (const float*)d_in[7];
    const float* bo    = (const float*)d_in[8];
    const float* ln1_g = (const float*)d_in[9];
    const float* ln1_b = (const float*)d_in[10];
    const float* ln2_g = (const float*)d_in[11];
    const float* ln2_b = (const float*)d_in[12];
    float* out = (float*)d_out;

    unsigned short* WtAll = (unsigned short*)d_ws;    // [4][512][512] bf16
    unsigned short* h_bf  = WtAll + 4 * 262144;       // [8192][512]
    unsigned short* Qb    = h_bf + 4194304;           // [64][1024][64]
    unsigned short* Kb    = Qb + 4194304;
    unsigned short* Vtg   = Kb + 4194304;             // [64][64][1024] transposed
    unsigned short* Ob    = Vtg + 4194304;            // [8192][512]
    unsigned short* Y0    = Ob + 4194304;             // [8192][512] bf16
    float* qsq = (float*)(Y0 + 4194304);              // [65536]
    float* ksq = qsq + 65536;

    // 1) weights -> bf16^T  +  LN1 -> bf16 (fused launch, wave-per-row LN)
    prep_kernel<<<256 + M_ROWS / 4, 256, 0, stream>>>(Wq, Wk, Wv, Wo, WtAll,
                                                      x, ln1_g, ln1_b, h_bf);

    // 2) fused QKV projection (N=1536) + scatter + sum-squares
    gemm128<1, 128><<<768, 256, 0, stream>>>(h_bf, WtAll, bq, bk, bv,
                                             Qb, Kb, Vtg, qsq, ksq);

    // 3) MFMA distance attention -> Ob [B,N,D] bf16 (32 q/wave)
    attn_kernel<<<512, 256, 0, stream>>>(Qb, Kb, Vtg, qsq, ksq, Ob);

    // 4) output projection -> bf16 Y0
    gemm128<0, 64><<<512, 256, 0, stream>>>(Ob, WtAll + 3 * 262144, bo,
                                            nullptr, nullptr, Y0,
                                            nullptr, nullptr, nullptr, nullptr);

    // 5) residual + post-norm (wave-per-row)
    ln2_kernel<<<M_ROWS / 4, 256, 0, stream>>>(Y0, x, ln2_g, ln2_b, out);
}